// Round 12
// baseline (73.502 us; speedup 1.0000x reference)
//
#include <hip/hip_runtime.h>

#define NSUB   10000
#define NCLS   17
#define NG     500
#define NE     80000
#define HIDN   8
#define NEG_SLOPE 0.2f

typedef __attribute__((ext_vector_type(8))) short short8;
typedef __attribute__((ext_vector_type(4))) float f32x4;

// ws layout (float units)
#define OFF_SP   0                        // NSUB*32: {xl[8], P[17], 0 x7} per node
#define OFF_DP   (OFF_SP + NSUB*32)       // NSUB*32: {xr[8], logP[17], 0 x7} per node
#define OFF_NUM  (OFF_DP + NSUB*32)       // NSUB
#define OFF_DEN  (OFF_NUM + NSUB)         // NSUB
#define OFF_LLP  (OFF_DEN + NSUB)         // 625 per-tile ll partials

__device__ __forceinline__ unsigned short f2bf(float f) {
    unsigned u = __float_as_uint(f);
    u += 0x7FFFu + ((u >> 16) & 1u);      // round-to-nearest-even
    return (unsigned short)(u >> 16);
}

#define MFMA16 __builtin_amdgcn_mfma_f32_16x16x32_bf16

// ---- fused prep+cell: register-built B fragments, MFMA GEMM, epilogue ----
// B columns (our packing): 0..16 = 1/Var (B2-path), 17..33 = Mu/Var,
// 34..41 = Wl, 42..49 = Wr, 50..63 = 0.  Fragment (ks, nt): lane holds
// col = nt*16 + j, k = ks*32 + grp*8 + e.  nt=0 of the B1-path is all-zero
// (cols 0..15) -> its MFMA is dropped (5 MFMA/kstep instead of 6).
__launch_bounds__(256)
__global__ void k_cell(const float* __restrict__ x, const int* __restrict__ sidx,
                       const float* __restrict__ Wp, const float* __restrict__ Spar,
                       const float* __restrict__ blv, const float* __restrict__ brv,
                       const float* __restrict__ Mu, const float* __restrict__ Var,
                       const float* __restrict__ Wl, const float* __restrict__ Wr,
                       float* __restrict__ out, float* __restrict__ SP,
                       float* __restrict__ DP, float* __restrict__ NUMDEN,
                       float* __restrict__ LLPART) {
    const int tid = threadIdx.x;

    // fold the zeroing of NUM/DEN and out[0..1] into this (first) dispatch;
    // kernel-end release makes them visible to k_edge / k_node.
    const int gid = blockIdx.x * 256 + tid;
    if (gid < 2 * NSUB) NUMDEN[gid] = 0.f;
    if (gid < 2) out[gid] = 0.f;

    const int w = tid >> 6, l = tid & 63;
    const int grp = l >> 4, j = l & 15;
    const int rowbase = blockIdx.x * 16;             // 625 tiles exactly
    const int ks0 = w * 4;
    const float* xr = x + (size_t)(rowbase + j) * NG;

    f32x4 a0 = {0,0,0,0}, a1 = {0,0,0,0}, a2 = {0,0,0,0}, a3 = {0,0,0,0};

    #pragma unroll
    for (int i = 0; i < 4; i++) {
        const int ks = ks0 + i;
        const int g0 = ks * 32 + grp * 8;

        // ---- A fragments (x and x^2, bf16) ----
        float4 v0 = {0.f,0.f,0.f,0.f}, v1 = {0.f,0.f,0.f,0.f};
        if (ks < 15) {
            v0 = *reinterpret_cast<const float4*>(xr + g0);
            v1 = *reinterpret_cast<const float4*>(xr + g0 + 4);
        } else {                                     // genes 480..499 valid
            if (g0 <= 496) v0 = *reinterpret_cast<const float4*>(xr + g0);
            if (g0 <= 488) v1 = *reinterpret_cast<const float4*>(xr + g0 + 4);
        }
        const float xv[8] = { v0.x, v0.y, v0.z, v0.w, v1.x, v1.y, v1.z, v1.w };
        short8 fa, fb;
        #pragma unroll
        for (int e = 0; e < 8; e++) {
            fa[e] = (short)f2bf(xv[e]);
            fb[e] = (short)f2bf(xv[e] * xv[e]);
        }

        // ---- B fragments, built in registers (same formulas as old k_prep) ----
        short8 q1, q2, q3, r0, r1;
        #pragma unroll
        for (int e = 0; e < 8; e++) {
            const int g = g0 + e;
            const bool gv = (g < NG);
            float v;
            // q1: col = 16 + j -> j>=1: class c = j-1 (Mu/Var); j==0 -> col16 (B1 zero)
            v = 0.f;
            if (gv && j >= 1)
                v = Mu[(j - 1) * NG + g] * __builtin_amdgcn_rcpf(Var[(j - 1) * NG + g]);
            q1[e] = (short)f2bf(v);
            // q2: col = 32 + j -> j<2: class 15+j; j in 2..9: Wl[:,j-2]; j in 10..15: Wr[:,j-10]
            v = 0.f;
            if (gv) {
                if (j < 2)
                    v = Mu[(15 + j) * NG + g] * __builtin_amdgcn_rcpf(Var[(15 + j) * NG + g]);
                else if (j < 10)
                    v = Wl[g * HIDN + (j - 2)];
                else
                    v = Wr[g * HIDN + (j - 10)];
            }
            q2[e] = (short)f2bf(v);
            // q3: col = 48 + j -> j<2: Wr[:,6+j]; else 0
            v = 0.f;
            if (gv && j < 2) v = Wr[g * HIDN + 6 + j];
            q3[e] = (short)f2bf(v);
            // r0: col = j (0..15): 1/Var[j]
            v = gv ? __builtin_amdgcn_rcpf(Var[j * NG + g]) : 0.f;
            r0[e] = (short)f2bf(v);
            // r1: col = 16 + j -> j==0: 1/Var[16]; else 0
            v = 0.f;
            if (gv && j == 0) v = __builtin_amdgcn_rcpf(Var[16 * NG + g]);
            r1[e] = (short)f2bf(v);
        }

        a1 = MFMA16(fa, q1, a1, 0, 0, 0);
        a2 = MFMA16(fa, q2, a2, 0, 0, 0);
        a3 = MFMA16(fa, q3, a3, 0, 0, 0);
        a0 = MFMA16(fb, r0, a0, 0, 0, 0);
        a1 = MFMA16(fb, r1, a1, 0, 0, 0);
    }

    // C layout: row = grp*4 + r, col = nt*16 + j (m89-verified)
    __shared__ float ct[4][16][68];
    #pragma unroll
    for (int r = 0; r < 4; r++) {
        ct[w][grp * 4 + r][j]      = a0[r];
        ct[w][grp * 4 + r][16 + j] = a1[r];
        ct[w][grp * 4 + r][32 + j] = a2[r];
        ct[w][grp * 4 + r][48 + j] = a3[r];
    }
    __syncthreads();

    if (w == 0) {
        float ll = 0.f;
        if (l < 16) {
            const int cell = rowbase + l;
            const int idx = sidx[cell];
            const float* wrow = Wp + (size_t)idx * NCLS;
            float p[NCLS];
            float mx = -1e30f;
            #pragma unroll
            for (int c = 0; c < NCLS; c++) { p[c] = wrow[c]; mx = fmaxf(mx, p[c]); }
            float sum = 0.f;
            #pragma unroll
            for (int c = 0; c < NCLS; c++) { p[c] = __expf(p[c] - mx); sum += p[c]; }
            const float inv = 1.0f / sum;
            const float s = Spar[idx];
            float* orow = out + 2 + (size_t)cell * NCLS;
            float* sp   = SP + (size_t)cell * 32;
            float* dp   = DP + (size_t)cell * 32;
            float ll_c = 0.f;
            #pragma unroll
            for (int c = 0; c < NCLS; c++) {
                p[c] *= inv;
                const float lg = __logf(p[c] + 1e-8f);
                orow[c]    = p[c];
                sp[8 + c]  = p[c];
                dp[8 + c]  = lg;
                const float T1 = ct[0][l][c] + ct[1][l][c] + ct[2][l][c] + ct[3][l][c];
                const float T2 = ct[0][l][NCLS + c] + ct[1][l][NCLS + c]
                               + ct[2][l][NCLS + c] + ct[3][l][NCLS + c];
                ll_c += p[c] * (-0.5f * T1 + s * T2);   // D-term added in k_node
            }
            ll = ll_c;
            #pragma unroll
            for (int q = 25; q < 32; q++) { sp[q] = 0.f; dp[q] = 0.f; }
            #pragma unroll
            for (int h = 0; h < HIDN; h++) {
                sp[h] = ct[0][l][34 + h] + ct[1][l][34 + h]
                      + ct[2][l][34 + h] + ct[3][l][34 + h] + blv[h];
                dp[h] = ct[0][l][42 + h] + ct[1][l][42 + h]
                      + ct[2][l][42 + h] + ct[3][l][42 + h] + brv[h];
            }
        }
        #pragma unroll
        for (int o = 32; o; o >>= 1) ll += __shfl_xor(ll, o);
        if (l == 0) LLPART[blockIdx.x] = ll;          // plain store, summed in k_node
    }
}

// ---- edge pass (round-9 exact): packed gathers, no max-shift, NUM/DEN atomics ----
__global__ void k_edge(const int* __restrict__ ei, const float* __restrict__ att,
                       const float* __restrict__ SP, const float* __restrict__ DP,
                       float* __restrict__ NUM, float* __restrict__ DEN) {
    const int k = blockIdx.x * 256 + threadIdx.x;
    if (k >= NE) return;
    const int s = ei[k], d = ei[NE + k];
    const float4* sp = reinterpret_cast<const float4*>(SP + (size_t)s * 32);
    const float4* dp = reinterpret_cast<const float4*>(DP + (size_t)d * 32);
    const float4 xa0 = sp[0], xa1 = sp[1];
    const float4 xb0 = dp[0], xb1 = dp[1];
    const float hv[8] = { xa0.x + xb0.x, xa0.y + xb0.y, xa0.z + xb0.z, xa0.w + xb0.w,
                          xa1.x + xb1.x, xa1.y + xb1.y, xa1.z + xb1.z, xa1.w + xb1.w };
    float e = 0.f;
    #pragma unroll
    for (int h = 0; h < HIDN; h++) {
        const float v = hv[h];
        e += ((v > 0.f) ? v : NEG_SLOPE * v) * att[h];
    }
    const float ex = __expf(e);            // no max-shift: |e| <~ 8, exp in f32 range
    float wgt = 0.f;
    #pragma unroll
    for (int q = 2; q < 7; q++) {          // P[17]+pad dot logP[17]+pad
        const float4 ps = sp[q];
        const float4 ld = dp[q];
        wgt += ps.x * ld.x + ps.y * ld.y + ps.z * ld.z + ps.w * ld.w;
    }
    atomicAdd(NUM + d, ex * wgt);
    atomicAdd(DEN + d, ex);
}

// ---- node pass: ce_space sum + ll_prot D-term + LLPART fold ----
__global__ void k_node(const float* __restrict__ NUM, const float* __restrict__ DEN,
                       const float* __restrict__ Mu, const float* __restrict__ Var,
                       const int* __restrict__ sidx, const float* __restrict__ Spar,
                       const float* __restrict__ LLPART, float* __restrict__ out) {
    const int tid = threadIdx.x;

    // per-block D[17] = sum_g Mu^2/Var (redundant per block; 8500 rcp-fma)
    __shared__ float sD[17];
    if (tid < 17) sD[tid] = 0.f;
    __syncthreads();
    if (tid < 255) {                       // 15 slices x 17 classes
        const int c = tid % 17, slice = tid / 17;
        const int gs = slice * 34;
        const int ge = (gs + 34 < NG) ? gs + 34 : NG;
        float acc = 0.f;
        for (int g = gs; g < ge; g++) {
            const float m = Mu[c * NG + g];
            acc += m * m * __builtin_amdgcn_rcpf(Var[c * NG + g]);
        }
        atomicAdd(&sD[c], acc);
    }
    __syncthreads();

    const int n = blockIdx.x * 256 + tid;
    float v_ce = 0.f, v_ll = 0.f;
    if (n < NSUB) {
        const float dd = DEN[n];
        v_ce = (dd > 0.f) ? NUM[n] / dd : 0.f;
        const float s = Spar[sidx[n]];
        const float* pr = out + 2 + (size_t)n * NCLS;
        float dot = 0.f;
        #pragma unroll
        for (int c = 0; c < NCLS; c++) dot += pr[c] * sD[c];
        v_ll = -0.5f * s * s * dot;
        if (n < 625) v_ll += LLPART[n];    // fold tile partials (n<625 subset of n<NSUB)
    }
    #pragma unroll
    for (int o = 32; o; o >>= 1) { v_ce += __shfl_xor(v_ce, o); v_ll += __shfl_xor(v_ll, o); }
    if ((tid & 63) == 0) {
        atomicAdd(out,     v_ll * (1.0f / NSUB));
        atomicAdd(out + 1, -v_ce * (1.0f / NSUB));
    }
}

extern "C" void kernel_launch(void* const* d_in, const int* in_sizes, int n_in,
                              void* d_out, int out_size, void* d_ws, size_t ws_size,
                              hipStream_t stream) {
    const float* x    = (const float*)d_in[0];
    const float* Mu   = (const float*)d_in[1];
    const float* Var  = (const float*)d_in[2];
    const int*   ei   = (const int*)d_in[3];
    const int*   sidx = (const int*)d_in[4];
    const float* Wp   = (const float*)d_in[5];
    const float* Sp   = (const float*)d_in[6];
    const float* Wl   = (const float*)d_in[7];
    const float* bl   = (const float*)d_in[8];
    const float* Wr   = (const float*)d_in[9];
    const float* br   = (const float*)d_in[10];
    const float* att  = (const float*)d_in[11];
    float* out = (float*)d_out;
    float* ws  = (float*)d_ws;

    float* SP   = ws + OFF_SP;
    float* DP   = ws + OFF_DP;
    float* NUM  = ws + OFF_NUM;
    float* DEN  = ws + OFF_DEN;
    float* LLP  = ws + OFF_LLP;

    (void)in_sizes; (void)n_in; (void)out_size; (void)ws_size;

    k_cell<<<NSUB / 16, 256, 0, stream>>>(x, sidx, Wp, Sp, bl, br, Mu, Var, Wl, Wr,
                                          out, SP, DP, NUM, LLP);
    k_edge<<<(NE + 255) / 256, 256, 0, stream>>>(ei, att, SP, DP, NUM, DEN);
    k_node<<<(NSUB + 255) / 256, 256, 0, stream>>>(NUM, DEN, Mu, Var, sidx, Sp,
                                                   LLP, out);
}

// Round 13
// 47.493 us; speedup vs baseline: 1.5477x; 1.5477x over previous
//
#include <hip/hip_runtime.h>

#define NSUB   10000
#define NCLS   17
#define NG     500
#define NE     80000
#define HIDN   8
#define NEG_SLOPE 0.2f

typedef __attribute__((ext_vector_type(8))) short short8;
typedef __attribute__((ext_vector_type(4))) float f32x4;

// ws layout (float units)
#define OFF_B1   0                        // 512x64 bf16 = 16384 float slots
#define OFF_B2   16384                    // 512x32 bf16 = 8192 float slots
#define OFF_D    (OFF_B2 + 8192)          // 32
#define OFF_SP   (OFF_D + 32)             // NSUB*32: {xl[8], P[17], 0 x7} per node
#define OFF_DP   (OFF_SP + NSUB*32)       // NSUB*32: {xr[8], logP[17], 0 x7} per node
#define OFF_NUM  (OFF_DP + NSUB*32)       // NSUB
#define OFF_DEN  (OFF_NUM + NSUB)         // NSUB

__device__ __forceinline__ unsigned short f2bf(float f) {
    unsigned u = __float_as_uint(f);
    u += 0x7FFFu + ((u >> 16) & 1u);      // round-to-nearest-even
    return (unsigned short)(u >> 16);
}

#define MFMA16 __builtin_amdgcn_mfma_f32_16x16x32_bf16

// ---- prep: B1/B2 bf16 fragments, D[c], zero out[0..1] + NUM/DEN ----
__global__ void k_prep(const float* __restrict__ Mu, const float* __restrict__ Var,
                       const float* __restrict__ Wl, const float* __restrict__ Wr,
                       unsigned short* __restrict__ B1, unsigned short* __restrict__ B2,
                       float* __restrict__ D, float* __restrict__ zeroBase,
                       float* __restrict__ out) {
    const int b = blockIdx.x;
    if (b < 4) {
        const int t = b * 256 + threadIdx.x;        // 1024 threads = 16 ksteps * 64 lanes
        const int ks = t >> 6, lane = t & 63;
        const int fgrp = lane >> 4, fj = lane & 15;
        unsigned short v1[4][8], v2[2][8];
        #pragma unroll
        for (int e = 0; e < 8; e++) {
            const int g = ks * 32 + fgrp * 8 + e;
            const bool gv = (g < NG);
            #pragma unroll
            for (int nt = 0; nt < 4; nt++) {
                const int col = nt * 16 + fj;
                float v = 0.f;
                if (gv) {
                    if (col >= 17 && col < 34)      v = Mu[(col - 17) * NG + g] / Var[(col - 17) * NG + g];
                    else if (col >= 34 && col < 42) v = Wl[g * HIDN + (col - 34)];
                    else if (col >= 42 && col < 50) v = Wr[g * HIDN + (col - 42)];
                }
                v1[nt][e] = f2bf(v);
            }
            #pragma unroll
            for (int nt = 0; nt < 2; nt++) {
                const int col = nt * 16 + fj;
                float v = 0.f;
                if (gv && col < NCLS) v = 1.0f / Var[col * NG + g];
                v2[nt][e] = f2bf(v);
            }
        }
        #pragma unroll
        for (int nt = 0; nt < 4; nt++)
            *reinterpret_cast<short8*>(B1 + (size_t)((ks * 4 + nt) * 64 + lane) * 8) =
                *reinterpret_cast<short8*>(v1[nt]);
        #pragma unroll
        for (int nt = 0; nt < 2; nt++)
            *reinterpret_cast<short8*>(B2 + (size_t)((ks * 2 + nt) * 64 + lane) * 8) =
                *reinterpret_cast<short8*>(v2[nt]);
    } else if (b < 21) {
        const int c = b - 4;
        float s = 0.f;
        for (int g = threadIdx.x; g < NG; g += 256) {
            const float m = Mu[c * NG + g];
            s += m * m / Var[c * NG + g];
        }
        __shared__ float red[4];
        #pragma unroll
        for (int o = 32; o; o >>= 1) s += __shfl_xor(s, o);
        const int w = threadIdx.x >> 6, l = threadIdx.x & 63;
        if (l == 0) red[w] = s;
        __syncthreads();
        if (threadIdx.x == 0) D[c] = red[0] + red[1] + red[2] + red[3];
    } else {
        const int i = (b - 21) * 256 + threadIdx.x;   // zero NUM/DEN (2*NSUB)
        if (i < 2 * NSUB) zeroBase[i] = 0.f;
        if (b == 21 && threadIdx.x < 2) out[threadIdx.x] = 0.f;
    }
}

// ---- per-cell: MFMA GEMM, 1 tile (16 cells) per block, K split across 8 waves ----
// 512 threads: wave w owns ksteps {2w, 2w+1}; wave 7's second kstep is the
// ragged tail (genes 480..499). Halves the per-wave serial K-chain and doubles
// resident waves vs the 4-way split (latency-bound fix).
__launch_bounds__(512)
__global__ void k_cell(const float* __restrict__ x, const int* __restrict__ sidx,
                       const float* __restrict__ Wp, const float* __restrict__ Sp,
                       const float* __restrict__ blv, const float* __restrict__ brv,
                       const unsigned short* __restrict__ B1,
                       const unsigned short* __restrict__ B2,
                       const float* __restrict__ D,
                       float* __restrict__ out, float* __restrict__ SP,
                       float* __restrict__ DP) {
    const int tid = threadIdx.x;
    const int w = tid >> 6, l = tid & 63;
    const int grp = l >> 4, j = l & 15;
    const int rowbase = blockIdx.x * 16;             // 625 tiles exactly

    f32x4 a0 = {0,0,0,0}, a1 = {0,0,0,0}, a2 = {0,0,0,0}, a3 = {0,0,0,0};
    const float* xr = x + (size_t)(rowbase + j) * NG;
    const short8* b1 = reinterpret_cast<const short8*>(B1);
    const short8* b2 = reinterpret_cast<const short8*>(B2);

#define KSTEP(ks, fa, fb)                                                \
    {                                                                    \
        const short8* p1 = b1 + (size_t)((ks) * 4) * 64 + l;             \
        const short8* p2 = b2 + (size_t)((ks) * 2) * 64 + l;             \
        a0 = MFMA16(fa, p1[0],   a0, 0, 0, 0);                           \
        a1 = MFMA16(fa, p1[64],  a1, 0, 0, 0);                           \
        a2 = MFMA16(fa, p1[128], a2, 0, 0, 0);                           \
        a3 = MFMA16(fa, p1[192], a3, 0, 0, 0);                           \
        a0 = MFMA16(fb, p2[0],   a0, 0, 0, 0);                           \
        a1 = MFMA16(fb, p2[64],  a1, 0, 0, 0);                           \
    }

    const int ks0 = w * 2;
    {   // first kstep (always full)
        const int g0 = ks0 * 32 + grp * 8;
        const float4 v0 = *reinterpret_cast<const float4*>(xr + g0);
        const float4 v1 = *reinterpret_cast<const float4*>(xr + g0 + 4);
        const float xv[8] = { v0.x, v0.y, v0.z, v0.w, v1.x, v1.y, v1.z, v1.w };
        short8 fa, fb;
        #pragma unroll
        for (int e = 0; e < 8; e++) { fa[e] = (short)f2bf(xv[e]); fb[e] = (short)f2bf(xv[e] * xv[e]); }
        KSTEP(ks0, fa, fb);
    }
    if (w < 7) {                                     // second kstep (full)
        const int ks = ks0 + 1;
        const int g0 = ks * 32 + grp * 8;
        const float4 v0 = *reinterpret_cast<const float4*>(xr + g0);
        const float4 v1 = *reinterpret_cast<const float4*>(xr + g0 + 4);
        const float xv[8] = { v0.x, v0.y, v0.z, v0.w, v1.x, v1.y, v1.z, v1.w };
        short8 fa, fb;
        #pragma unroll
        for (int e = 0; e < 8; e++) { fa[e] = (short)f2bf(xv[e]); fb[e] = (short)f2bf(xv[e] * xv[e]); }
        KSTEP(ks, fa, fb);
    } else {                                         // ks = 15 tail: genes 480..499 valid
        const int g0 = 480 + grp * 8;
        float4 v0 = {0,0,0,0}, v1 = {0,0,0,0};
        if (g0 <= 496) v0 = *reinterpret_cast<const float4*>(xr + g0);
        if (g0 <= 488) v1 = *reinterpret_cast<const float4*>(xr + g0 + 4);
        const float xv[8] = { v0.x, v0.y, v0.z, v0.w, v1.x, v1.y, v1.z, v1.w };
        short8 fa, fb;
        #pragma unroll
        for (int e = 0; e < 8; e++) { fa[e] = (short)f2bf(xv[e]); fb[e] = (short)f2bf(xv[e] * xv[e]); }
        KSTEP(15, fa, fb);
    }
#undef KSTEP

    // C layout: row = grp*4 + r, col = nt*16 + j (m89-verified)
    __shared__ float ct[8][16][68];
    #pragma unroll
    for (int r = 0; r < 4; r++) {
        ct[w][grp * 4 + r][j]      = a0[r];
        ct[w][grp * 4 + r][16 + j] = a1[r];
        ct[w][grp * 4 + r][32 + j] = a2[r];
        ct[w][grp * 4 + r][48 + j] = a3[r];
    }
    __syncthreads();

    if (w == 0) {
        float ll = 0.f;
        if (l < 16) {
            const int cell = rowbase + l;
            const int idx = sidx[cell];
            const float* wrow = Wp + (size_t)idx * NCLS;
            float p[NCLS];
            float mx = -1e30f;
            #pragma unroll
            for (int c = 0; c < NCLS; c++) { p[c] = wrow[c]; mx = fmaxf(mx, p[c]); }
            float sum = 0.f;
            #pragma unroll
            for (int c = 0; c < NCLS; c++) { p[c] = __expf(p[c] - mx); sum += p[c]; }
            const float inv = 1.0f / sum;
            const float s = Sp[idx];
            float* orow = out + 2 + (size_t)cell * NCLS;
            float* sp   = SP + (size_t)cell * 32;
            float* dp   = DP + (size_t)cell * 32;
            float ll_c = 0.f;
            #pragma unroll
            for (int c = 0; c < NCLS; c++) {
                p[c] *= inv;
                const float lg = __logf(p[c] + 1e-8f);
                orow[c]    = p[c];
                sp[8 + c]  = p[c];
                dp[8 + c]  = lg;
                float T1 = 0.f, T2 = 0.f;
                #pragma unroll
                for (int q = 0; q < 8; q++) {
                    T1 += ct[q][l][c];
                    T2 += ct[q][l][NCLS + c];
                }
                ll_c += p[c] * (-0.5f * T1 + s * T2 - 0.5f * s * s * D[c]);
            }
            ll = ll_c;
            #pragma unroll
            for (int q = 25; q < 32; q++) { sp[q] = 0.f; dp[q] = 0.f; }
            #pragma unroll
            for (int h = 0; h < HIDN; h++) {
                float xl = blv[h], xrv = brv[h];
                #pragma unroll
                for (int q = 0; q < 8; q++) {
                    xl  += ct[q][l][34 + h];
                    xrv += ct[q][l][42 + h];
                }
                sp[h] = xl;
                dp[h] = xrv;
            }
        }
        #pragma unroll
        for (int o = 32; o; o >>= 1) ll += __shfl_xor(ll, o);
        if (l == 0) atomicAdd(out, ll * (1.0f / NSUB));
    }
}

// ---- fused edge pass: 2-line packed gathers per side, no max-shift ----
__global__ void k_edge(const int* __restrict__ ei, const float* __restrict__ att,
                       const float* __restrict__ SP, const float* __restrict__ DP,
                       float* __restrict__ NUM, float* __restrict__ DEN) {
    const int k = blockIdx.x * 256 + threadIdx.x;
    if (k >= NE) return;
    const int s = ei[k], d = ei[NE + k];
    const float4* sp = reinterpret_cast<const float4*>(SP + (size_t)s * 32);
    const float4* dp = reinterpret_cast<const float4*>(DP + (size_t)d * 32);
    const float4 xa0 = sp[0], xa1 = sp[1];
    const float4 xb0 = dp[0], xb1 = dp[1];
    const float hv[8] = { xa0.x + xb0.x, xa0.y + xb0.y, xa0.z + xb0.z, xa0.w + xb0.w,
                          xa1.x + xb1.x, xa1.y + xb1.y, xa1.z + xb1.z, xa1.w + xb1.w };
    float e = 0.f;
    #pragma unroll
    for (int h = 0; h < HIDN; h++) {
        const float v = hv[h];
        e += ((v > 0.f) ? v : NEG_SLOPE * v) * att[h];
    }
    const float ex = __expf(e);            // no max-shift: |e| <~ 8, exp in f32 range
    float wgt = 0.f;
    #pragma unroll
    for (int q = 2; q < 7; q++) {          // P[17]+pad dot logP[17]+pad
        const float4 ps = sp[q];
        const float4 ld = dp[q];
        wgt += ps.x * ld.x + ps.y * ld.y + ps.z * ld.z + ps.w * ld.w;
    }
    atomicAdd(NUM + d, ex * wgt);
    atomicAdd(DEN + d, ex);
}

// ---- node pass: ce_space = -sum(num/den)/n ----
__global__ void k_node(const float* __restrict__ NUM, const float* __restrict__ DEN,
                       float* __restrict__ out) {
    const int n = blockIdx.x * 256 + threadIdx.x;
    float v = 0.f;
    if (n < NSUB) {
        const float dd = DEN[n];
        if (dd > 0.f) v = NUM[n] / dd;
    }
    #pragma unroll
    for (int o = 32; o; o >>= 1) v += __shfl_xor(v, o);
    if ((threadIdx.x & 63) == 0 && v != 0.f) atomicAdd(out + 1, -v * (1.0f / NSUB));
}

extern "C" void kernel_launch(void* const* d_in, const int* in_sizes, int n_in,
                              void* d_out, int out_size, void* d_ws, size_t ws_size,
                              hipStream_t stream) {
    const float* x    = (const float*)d_in[0];
    const float* Mu   = (const float*)d_in[1];
    const float* Var  = (const float*)d_in[2];
    const int*   ei   = (const int*)d_in[3];
    const int*   sidx = (const int*)d_in[4];
    const float* Wp   = (const float*)d_in[5];
    const float* Sp   = (const float*)d_in[6];
    const float* Wl   = (const float*)d_in[7];
    const float* bl   = (const float*)d_in[8];
    const float* Wr   = (const float*)d_in[9];
    const float* br   = (const float*)d_in[10];
    const float* att  = (const float*)d_in[11];
    float* out = (float*)d_out;
    float* ws  = (float*)d_ws;

    unsigned short* B1 = (unsigned short*)(ws + OFF_B1);
    unsigned short* B2 = (unsigned short*)(ws + OFF_B2);
    float* D    = ws + OFF_D;
    float* SP   = ws + OFF_SP;
    float* DP   = ws + OFF_DP;
    float* NUM  = ws + OFF_NUM;
    float* DEN  = ws + OFF_DEN;

    (void)in_sizes; (void)n_in; (void)out_size; (void)ws_size;

    k_prep<<<100, 256, 0, stream>>>(Mu, Var, Wl, Wr, B1, B2, D, NUM, out);
    k_cell<<<NSUB / 16, 512, 0, stream>>>(x, sidx, Wp, Sp, bl, br, B1, B2, D,
                                          out, SP, DP);
    k_edge<<<(NE + 255) / 256, 256, 0, stream>>>(ei, att, SP, DP, NUM, DEN);
    k_node<<<(NSUB + 255) / 256, 256, 0, stream>>>(NUM, DEN, out);
}

// Round 14
// 45.365 us; speedup vs baseline: 1.6202x; 1.0469x over previous
//
#include <hip/hip_runtime.h>

#define NSUB   10000
#define NCLS   17
#define NG     500
#define NE     80000
#define HIDN   8
#define NEG_SLOPE 0.2f

typedef __attribute__((ext_vector_type(8))) short short8;
typedef __attribute__((ext_vector_type(4))) float f32x4;

// ws layout (float units)
#define OFF_B1   0                        // 512x64 bf16 = 16384 float slots
#define OFF_B2   16384                    // 512x32 bf16 = 8192 float slots
#define OFF_D    (OFF_B2 + 8192)          // 32
#define OFF_SP   (OFF_D + 32)             // NSUB*32: {xl[8], P[17], 0 x7} per node
#define OFF_DP   (OFF_SP + NSUB*32)       // NSUB*32: {xr[8], logP[17], 0 x7} per node
#define OFF_NUM  (OFF_DP + NSUB*32)       // NSUB
#define OFF_DEN  (OFF_NUM + NSUB)         // NSUB

__device__ __forceinline__ unsigned short f2bf(float f) {
    unsigned u = __float_as_uint(f);
    u += 0x7FFFu + ((u >> 16) & 1u);      // round-to-nearest-even
    return (unsigned short)(u >> 16);
}

#define MFMA16 __builtin_amdgcn_mfma_f32_16x16x32_bf16

// ---- prep v2: fragment build parallelized to 16 blocks w/ LDS-staged coalesced reads.
// Old version ran the build in 4 blocks with 48 class-strided cold loads per thread
// (latency-serial, ~no TLP). Now: block ks stages its 32-gene slice of Mu/Var/Wl/Wr
// coalesced into LDS (one cold round-trip), then one wave emits fragments from LDS.
__global__ void k_prep(const float* __restrict__ Mu, const float* __restrict__ Var,
                       const float* __restrict__ Wl, const float* __restrict__ Wr,
                       unsigned short* __restrict__ B1, unsigned short* __restrict__ B2,
                       float* __restrict__ D, float* __restrict__ zeroBase,
                       float* __restrict__ out) {
    const int b = blockIdx.x;
    const int tid = threadIdx.x;
    if (b < 16) {
        const int ks = b;                             // kstep this block builds
        __shared__ float sMu[NCLS][33], sVa[NCLS][33];
        __shared__ float sWl[32][8], sWr[32][8];
        // Mu/Var slice: 17 classes x 32 genes, strip-coalesced (128 B per class row)
        for (int t = tid; t < NCLS * 32; t += 256) {
            const int c = t >> 5, gg = t & 31;
            const int g = ks * 32 + gg;
            sMu[c][gg] = (g < NG) ? Mu[c * NG + g] : 0.f;
            sVa[c][gg] = (g < NG) ? Var[c * NG + g] : 1.f;
        }
        // Wl/Wr slice: 32 genes x 8 hid, fully coalesced (g-major contiguous)
        {
            const int gg = tid >> 3, h = tid & 7;
            const int g = ks * 32 + gg;
            sWl[gg][h] = (g < NG) ? Wl[g * HIDN + h] : 0.f;
            sWr[gg][h] = (g < NG) ? Wr[g * HIDN + h] : 0.f;
        }
        __syncthreads();
        if (tid < 64) {
            const int lane = tid;
            const int fgrp = lane >> 4, fj = lane & 15;
            unsigned short v1[4][8], v2[2][8];
            #pragma unroll
            for (int e = 0; e < 8; e++) {
                const int gg = fgrp * 8 + e;
                const bool gv = (ks * 32 + gg < NG);
                #pragma unroll
                for (int nt = 0; nt < 4; nt++) {
                    const int col = nt * 16 + fj;
                    float v = 0.f;
                    if (gv) {
                        if (col >= 17 && col < 34)      v = sMu[col - 17][gg] / sVa[col - 17][gg];
                        else if (col >= 34 && col < 42) v = sWl[gg][col - 34];
                        else if (col >= 42 && col < 50) v = sWr[gg][col - 42];
                    }
                    v1[nt][e] = f2bf(v);
                }
                #pragma unroll
                for (int nt = 0; nt < 2; nt++) {
                    const int col = nt * 16 + fj;
                    float v = 0.f;
                    if (gv && col < NCLS) v = 1.0f / sVa[col][gg];
                    v2[nt][e] = f2bf(v);
                }
            }
            #pragma unroll
            for (int nt = 0; nt < 4; nt++)
                *reinterpret_cast<short8*>(B1 + (size_t)((ks * 4 + nt) * 64 + lane) * 8) =
                    *reinterpret_cast<short8*>(v1[nt]);
            #pragma unroll
            for (int nt = 0; nt < 2; nt++)
                *reinterpret_cast<short8*>(B2 + (size_t)((ks * 2 + nt) * 64 + lane) * 8) =
                    *reinterpret_cast<short8*>(v2[nt]);
        }
    } else if (b < 33) {
        const int c = b - 16;
        float s = 0.f;
        for (int g = tid; g < NG; g += 256) {
            const float m = Mu[c * NG + g];
            s += m * m / Var[c * NG + g];
        }
        __shared__ float red[4];
        #pragma unroll
        for (int o = 32; o; o >>= 1) s += __shfl_xor(s, o);
        const int w = tid >> 6, l = tid & 63;
        if (l == 0) red[w] = s;
        __syncthreads();
        if (tid == 0) D[c] = red[0] + red[1] + red[2] + red[3];
    } else {
        const int i = (b - 33) * 256 + tid;           // zero NUM/DEN (2*NSUB)
        if (i < 2 * NSUB) zeroBase[i] = 0.f;
        if (b == 33 && tid < 2) out[tid] = 0.f;
    }
}

// ---- per-cell: MFMA GEMM, 1 tile (16 cells) per block, K split across 4 waves ----
// (round-9 exact, measured best)
__launch_bounds__(256)
__global__ void k_cell(const float* __restrict__ x, const int* __restrict__ sidx,
                       const float* __restrict__ Wp, const float* __restrict__ Sp,
                       const float* __restrict__ blv, const float* __restrict__ brv,
                       const unsigned short* __restrict__ B1,
                       const unsigned short* __restrict__ B2,
                       const float* __restrict__ D,
                       float* __restrict__ out, float* __restrict__ SP,
                       float* __restrict__ DP) {
    const int tid = threadIdx.x;
    const int w = tid >> 6, l = tid & 63;
    const int grp = l >> 4, j = l & 15;
    const int rowbase = blockIdx.x * 16;             // 625 tiles exactly

    f32x4 a0 = {0,0,0,0}, a1 = {0,0,0,0}, a2 = {0,0,0,0}, a3 = {0,0,0,0};
    const float* xr = x + (size_t)(rowbase + j) * NG;
    const short8* b1 = reinterpret_cast<const short8*>(B1);
    const short8* b2 = reinterpret_cast<const short8*>(B2);

#define KSTEP(ks, fa, fb)                                                \
    {                                                                    \
        const short8* p1 = b1 + (size_t)((ks) * 4) * 64 + l;             \
        const short8* p2 = b2 + (size_t)((ks) * 2) * 64 + l;             \
        a0 = MFMA16(fa, p1[0],   a0, 0, 0, 0);                           \
        a1 = MFMA16(fa, p1[64],  a1, 0, 0, 0);                           \
        a2 = MFMA16(fa, p1[128], a2, 0, 0, 0);                           \
        a3 = MFMA16(fa, p1[192], a3, 0, 0, 0);                           \
        a0 = MFMA16(fb, p2[0],   a0, 0, 0, 0);                           \
        a1 = MFMA16(fb, p2[64],  a1, 0, 0, 0);                           \
    }

    const int ks0 = w * 4;
    #pragma unroll
    for (int i = 0; i < 3; i++) {
        const int ks = ks0 + i;
        const int g0 = ks * 32 + grp * 8;
        const float4 v0 = *reinterpret_cast<const float4*>(xr + g0);
        const float4 v1 = *reinterpret_cast<const float4*>(xr + g0 + 4);
        const float xv[8] = { v0.x, v0.y, v0.z, v0.w, v1.x, v1.y, v1.z, v1.w };
        short8 fa, fb;
        #pragma unroll
        for (int e = 0; e < 8; e++) { fa[e] = (short)f2bf(xv[e]); fb[e] = (short)f2bf(xv[e] * xv[e]); }
        KSTEP(ks, fa, fb);
    }
    if (w < 3) {
        const int ks = ks0 + 3;
        const int g0 = ks * 32 + grp * 8;
        const float4 v0 = *reinterpret_cast<const float4*>(xr + g0);
        const float4 v1 = *reinterpret_cast<const float4*>(xr + g0 + 4);
        const float xv[8] = { v0.x, v0.y, v0.z, v0.w, v1.x, v1.y, v1.z, v1.w };
        short8 fa, fb;
        #pragma unroll
        for (int e = 0; e < 8; e++) { fa[e] = (short)f2bf(xv[e]); fb[e] = (short)f2bf(xv[e] * xv[e]); }
        KSTEP(ks, fa, fb);
    } else {                                         // ks = 15 tail: genes 480..499 valid
        const int g0 = 480 + grp * 8;
        float4 v0 = {0,0,0,0}, v1 = {0,0,0,0};
        if (g0 <= 496) v0 = *reinterpret_cast<const float4*>(xr + g0);
        if (g0 <= 488) v1 = *reinterpret_cast<const float4*>(xr + g0 + 4);
        const float xv[8] = { v0.x, v0.y, v0.z, v0.w, v1.x, v1.y, v1.z, v1.w };
        short8 fa, fb;
        #pragma unroll
        for (int e = 0; e < 8; e++) { fa[e] = (short)f2bf(xv[e]); fb[e] = (short)f2bf(xv[e] * xv[e]); }
        KSTEP(15, fa, fb);
    }
#undef KSTEP

    // C layout: row = grp*4 + r, col = nt*16 + j (m89-verified)
    __shared__ float ct[4][16][68];
    #pragma unroll
    for (int r = 0; r < 4; r++) {
        ct[w][grp * 4 + r][j]      = a0[r];
        ct[w][grp * 4 + r][16 + j] = a1[r];
        ct[w][grp * 4 + r][32 + j] = a2[r];
        ct[w][grp * 4 + r][48 + j] = a3[r];
    }
    __syncthreads();

    if (w == 0) {
        float ll = 0.f;
        if (l < 16) {
            const int cell = rowbase + l;
            const int idx = sidx[cell];
            const float* wrow = Wp + (size_t)idx * NCLS;
            float p[NCLS];
            float mx = -1e30f;
            #pragma unroll
            for (int c = 0; c < NCLS; c++) { p[c] = wrow[c]; mx = fmaxf(mx, p[c]); }
            float sum = 0.f;
            #pragma unroll
            for (int c = 0; c < NCLS; c++) { p[c] = __expf(p[c] - mx); sum += p[c]; }
            const float inv = 1.0f / sum;
            const float s = Sp[idx];
            float* orow = out + 2 + (size_t)cell * NCLS;
            float* sp   = SP + (size_t)cell * 32;
            float* dp   = DP + (size_t)cell * 32;
            float ll_c = 0.f;
            #pragma unroll
            for (int c = 0; c < NCLS; c++) {
                p[c] *= inv;
                const float lg = __logf(p[c] + 1e-8f);
                orow[c]    = p[c];
                sp[8 + c]  = p[c];
                dp[8 + c]  = lg;
                const float T1 = ct[0][l][c] + ct[1][l][c] + ct[2][l][c] + ct[3][l][c];
                const float T2 = ct[0][l][NCLS + c] + ct[1][l][NCLS + c]
                               + ct[2][l][NCLS + c] + ct[3][l][NCLS + c];
                ll_c += p[c] * (-0.5f * T1 + s * T2 - 0.5f * s * s * D[c]);
            }
            ll = ll_c;
            #pragma unroll
            for (int q = 25; q < 32; q++) { sp[q] = 0.f; dp[q] = 0.f; }
            #pragma unroll
            for (int h = 0; h < HIDN; h++) {
                sp[h] = ct[0][l][34 + h] + ct[1][l][34 + h]
                      + ct[2][l][34 + h] + ct[3][l][34 + h] + blv[h];
                dp[h] = ct[0][l][42 + h] + ct[1][l][42 + h]
                      + ct[2][l][42 + h] + ct[3][l][42 + h] + brv[h];
            }
        }
        #pragma unroll
        for (int o = 32; o; o >>= 1) ll += __shfl_xor(ll, o);
        if (l == 0) atomicAdd(out, ll * (1.0f / NSUB));
    }
}

// ---- fused edge pass: 2-line packed gathers per side, no max-shift ----
__global__ void k_edge(const int* __restrict__ ei, const float* __restrict__ att,
                       const float* __restrict__ SP, const float* __restrict__ DP,
                       float* __restrict__ NUM, float* __restrict__ DEN) {
    const int k = blockIdx.x * 256 + threadIdx.x;
    if (k >= NE) return;
    const int s = ei[k], d = ei[NE + k];
    const float4* sp = reinterpret_cast<const float4*>(SP + (size_t)s * 32);
    const float4* dp = reinterpret_cast<const float4*>(DP + (size_t)d * 32);
    const float4 xa0 = sp[0], xa1 = sp[1];
    const float4 xb0 = dp[0], xb1 = dp[1];
    const float hv[8] = { xa0.x + xb0.x, xa0.y + xb0.y, xa0.z + xb0.z, xa0.w + xb0.w,
                          xa1.x + xb1.x, xa1.y + xb1.y, xa1.z + xb1.z, xa1.w + xb1.w };
    float e = 0.f;
    #pragma unroll
    for (int h = 0; h < HIDN; h++) {
        const float v = hv[h];
        e += ((v > 0.f) ? v : NEG_SLOPE * v) * att[h];
    }
    const float ex = __expf(e);            // no max-shift: |e| <~ 8, exp in f32 range
    float wgt = 0.f;
    #pragma unroll
    for (int q = 2; q < 7; q++) {          // P[17]+pad dot logP[17]+pad
        const float4 ps = sp[q];
        const float4 ld = dp[q];
        wgt += ps.x * ld.x + ps.y * ld.y + ps.z * ld.z + ps.w * ld.w;
    }
    atomicAdd(NUM + d, ex * wgt);
    atomicAdd(DEN + d, ex);
}

// ---- node pass: ce_space = -sum(num/den)/n ----
__global__ void k_node(const float* __restrict__ NUM, const float* __restrict__ DEN,
                       float* __restrict__ out) {
    const int n = blockIdx.x * 256 + threadIdx.x;
    float v = 0.f;
    if (n < NSUB) {
        const float dd = DEN[n];
        if (dd > 0.f) v = NUM[n] / dd;
    }
    #pragma unroll
    for (int o = 32; o; o >>= 1) v += __shfl_xor(v, o);
    if ((threadIdx.x & 63) == 0 && v != 0.f) atomicAdd(out + 1, -v * (1.0f / NSUB));
}

extern "C" void kernel_launch(void* const* d_in, const int* in_sizes, int n_in,
                              void* d_out, int out_size, void* d_ws, size_t ws_size,
                              hipStream_t stream) {
    const float* x    = (const float*)d_in[0];
    const float* Mu   = (const float*)d_in[1];
    const float* Var  = (const float*)d_in[2];
    const int*   ei   = (const int*)d_in[3];
    const int*   sidx = (const int*)d_in[4];
    const float* Wp   = (const float*)d_in[5];
    const float* Sp   = (const float*)d_in[6];
    const float* Wl   = (const float*)d_in[7];
    const float* bl   = (const float*)d_in[8];
    const float* Wr   = (const float*)d_in[9];
    const float* br   = (const float*)d_in[10];
    const float* att  = (const float*)d_in[11];
    float* out = (float*)d_out;
    float* ws  = (float*)d_ws;

    unsigned short* B1 = (unsigned short*)(ws + OFF_B1);
    unsigned short* B2 = (unsigned short*)(ws + OFF_B2);
    float* D    = ws + OFF_D;
    float* SP   = ws + OFF_SP;
    float* DP   = ws + OFF_DP;
    float* NUM  = ws + OFF_NUM;
    float* DEN  = ws + OFF_DEN;

    (void)in_sizes; (void)n_in; (void)out_size; (void)ws_size;

    // 16 (frag, one kstep each) + 17 (D) + 79 (zero NUM/DEN + out[0..1]) = 112
    k_prep<<<112, 256, 0, stream>>>(Mu, Var, Wl, Wr, B1, B2, D, NUM, out);
    k_cell<<<NSUB / 16, 256, 0, stream>>>(x, sidx, Wp, Sp, bl, br, B1, B2, D,
                                          out, SP, DP);
    k_edge<<<(NE + 255) / 256, 256, 0, stream>>>(ei, att, SP, DP, NUM, DEN);
    k_node<<<(NSUB + 255) / 256, 256, 0, stream>>>(NUM, DEN, out);
}